// Round 20
// baseline (357.630 us; speedup 1.0000x reference)
//
#include <hip/hip_runtime.h>
#include <hip/hip_bf16.h>
#include <math.h>

#define B_TOTAL 40960
#define NGRP 20
#define GSZ 2048
#define CPART 4

typedef short short8 __attribute__((ext_vector_type(8)));
typedef float f32x4 __attribute__((ext_vector_type(4)));
typedef float f32x16 __attribute__((ext_vector_type(16)));
typedef _Float16 half8 __attribute__((ext_vector_type(8)));
typedef _Float16 half4 __attribute__((ext_vector_type(4)));

// ---------------- bf16 helpers (kNN path) ----------------
__device__ __forceinline__ unsigned short bf16rne(float v)
{
    unsigned int u = __float_as_uint(v);
    unsigned int r = (u + 0x7FFFu + ((u >> 16) & 1u)) >> 16;
    return (unsigned short)r;
}

__device__ __forceinline__ float bf2f(unsigned short h)
{
    return __uint_as_float((unsigned int)h << 16);
}

// ---------------- fp16 split helper (MLP path) ----------------
__device__ __forceinline__ void splitf16(const float* v, half8& hi, half8& lo)
{
    #pragma unroll
    for (int j = 0; j < 8; j++) {
        _Float16 h = (_Float16)v[j];
        hi[j] = h;
        lo[j] = (_Float16)(v[j] - (float)h);
    }
}

// ordered-float key
__device__ __forceinline__ unsigned int fkey(float f)
{
    unsigned int u = __float_as_uint(f);
    unsigned int m = (unsigned int)((int)u >> 31) | 0x80000000u;
    return u ^ m;
}

__device__ __forceinline__ void ins3p(unsigned int k, unsigned int i,
    unsigned int& k0, unsigned int& i0, unsigned int& k1, unsigned int& i1,
    unsigned int& k2, unsigned int& i2)
{
    bool c0 = k < k0;
    unsigned int tk = c0 ? k0 : k, ti = c0 ? i0 : i;
    k0 = c0 ? k : k0;  i0 = c0 ? i : i0;
    bool c1 = tk < k1;
    unsigned int sk = c1 ? k1 : tk, si = c1 ? i1 : ti;
    k1 = c1 ? tk : k1; i1 = c1 ? ti : i1;
    bool c2 = sk < k2;
    k2 = c2 ? sk : k2; i2 = c2 ? si : i2;
}

__device__ __forceinline__ void mergerow(unsigned int& k0, unsigned int& i0,
    unsigned int& k1, unsigned int& i1, unsigned int& k2, unsigned int& i2)
{
    #pragma unroll
    for (int m = 1; m <= 8; m <<= 1) {
        unsigned int ok0 = (unsigned int)__shfl_xor((int)k0, m);
        unsigned int oi0 = (unsigned int)__shfl_xor((int)i0, m);
        unsigned int ok1 = (unsigned int)__shfl_xor((int)k1, m);
        unsigned int oi1 = (unsigned int)__shfl_xor((int)i1, m);
        unsigned int ok2 = (unsigned int)__shfl_xor((int)k2, m);
        unsigned int oi2 = (unsigned int)__shfl_xor((int)i2, m);
        ins3p(ok0, oi0, k0, i0, k1, i1, k2, i2);
        ins3p(ok1, oi1, k0, i0, k1, i1, k2, i2);
        ins3p(ok2, oi2, k0, i0, k1, i1, k2, i2);
    }
}

// ---------------- weight prep helpers ----------------
__device__ __forceinline__ void do_wprep_trunk(int t, const float* __restrict__ w0,
    const float* __restrict__ wmid, const float* __restrict__ wskip,
    const float* __restrict__ wfin, _Float16* __restrict__ wfrag)
{
    const int CUMa[10] = {0,4,20,36,52,72,88,104,120,136};
    const int KCa[9]   = {4,16,16,16,20,16,16,16,16};
    int q = t >> 12;
    int L = 0;
    #pragma unroll
    for (int i = 0; i < 9; i++) if (q >= CUMa[i + 1]) L = i + 1;
    int cum = 0, kcn = 16;
    #pragma unroll
    for (int i = 0; i < 9; i++) if (L == i) { cum = CUMa[i]; kcn = KCa[i]; }
    int u = t - (cum << 12);
    int j = u & 7, lane = (u >> 3) & 63;
    int ckk = u >> 9;
    int kc = ckk % kcn, ct = ckk / kcn;
    int col = ct * 32 + (lane & 31);
    int k = kc * 16 + ((lane >> 5) << 3) + j;
    float w;
    if (L == 0)      w = (k < 63)  ? w0[k * 256 + col] : 0.f;
    else if (L == 4) w = (k < 256) ? wskip[(63 + k) * 256 + col]
                       : (k < 319) ? wskip[(k - 256) * 256 + col] : 0.f;
    else if (L == 8) w = wfin[k * 256 + col];
    else {
        int m = (L <= 3) ? (L - 1) : (L - 2);
        w = wmid[(size_t)m * 65536 + k * 256 + col];
    }
    wfrag[((size_t)cum << 12) + (size_t)ckk * 512 + lane * 8 + j] = (_Float16)w;
}

__device__ __forceinline__ void do_wprep_pq(int t, const float* __restrict__ src,
    int K, int KCN, _Float16* __restrict__ dst)
{
    int j = t & 7, lane = (t >> 3) & 63;
    int ckk = t >> 9;
    int kc = ckk % KCN, ct = ckk / KCN;
    int col = ct * 32 + (lane & 31);
    int k = kc * 16 + ((lane >> 5) << 3) + j;
    float w = 0.f;
    if (k < K) w = (col < 128) ? src[(size_t)k * 128 + col]
                               : src[(size_t)(K + k) * 128 + (col - 128)];
    dst[(size_t)ckk * 512 + lane * 8 + j] = (_Float16)w;
}

__device__ __forceinline__ void do_wprep_sq(int t, const float* __restrict__ src,
    _Float16* __restrict__ dst)
{
    int j = t & 7, lane = (t >> 3) & 63;
    int ckk = t >> 9;
    int kc = ckk & 7, ct = ckk >> 3;
    int col = ct * 32 + (lane & 31);
    int k = kc * 16 + ((lane >> 5) << 3) + j;
    dst[(size_t)ckk * 512 + lane * 8 + j] = (_Float16)src[(size_t)k * 128 + col];
}

// ---------------- fused front end ----------------
// blocks [0,20): per-group ballot scatter + in-block gather (bit-identical to old
//   k_scatter_det + k_gather outputs). blocks [20,700): weight preps.
// prep ranges (1024-thread blocks): trunk 544 | pq1 72 | pq2 32 | e1w2 16 | e2w2 16
__global__ __launch_bounds__(1024) void k_front(const int* __restrict__ bid,
    int* __restrict__ grp, const float* __restrict__ x,
    unsigned short* __restrict__ xbh, unsigned short* __restrict__ xbl,
    float* __restrict__ cn,
    const float* __restrict__ w0, const float* __restrict__ wmid,
    const float* __restrict__ wskip, const float* __restrict__ wfin,
    _Float16* __restrict__ wfrag,
    const float* __restrict__ e1w1, _Float16* __restrict__ wfpq1,
    const float* __restrict__ e2w1, _Float16* __restrict__ wfpq2,
    const float* __restrict__ e1w2, _Float16* __restrict__ wfe1,
    const float* __restrict__ e2w2, _Float16* __restrict__ wfe2)
{
    __shared__ int cnts[640];
    __shared__ int offs[640];
    __shared__ int ids[GSZ];
    __shared__ float tile[256][65];
    const int tid = threadIdx.x;
    const int b = blockIdx.x;

    if (b >= 20) {
        const int b2 = b - 20;
        if (b2 < 544) {
            do_wprep_trunk(b2 * 1024 + tid, w0, wmid, wskip, wfin, wfrag);
        } else if (b2 < 616) {
            do_wprep_pq((b2 - 544) * 1024 + tid, e1w1, 283, 18, wfpq1);
        } else if (b2 < 648) {
            do_wprep_pq((b2 - 616) * 1024 + tid, e2w1, 128, 8, wfpq2);
        } else if (b2 < 664) {
            do_wprep_sq((b2 - 648) * 1024 + tid, e1w2, wfe1);
        } else {
            do_wprep_sq((b2 - 664) * 1024 + tid, e2w2, wfe2);
        }
        return;
    }

    // -------- phase A: deterministic ballot-compaction scatter (group b) --------
    const int w = tid >> 6, lane = tid & 63;
    const int g = b;
    for (int c = 0; c < 40; c++) {
        int i = c * 1024 + tid;
        unsigned long long m = __ballot(bid[i] == g);
        if (lane == 0) cnts[c * 16 + w] = __popcll(m);
    }
    __syncthreads();
    if (w == 0) {
        int base = lane * 10;
        int loc[10];
        int s = 0;
        #pragma unroll
        for (int u = 0; u < 10; u++) { loc[u] = s; s += cnts[base + u]; }
        int incl = s;
        #pragma unroll
        for (int d = 1; d < 64; d <<= 1) {
            int t = __shfl_up(incl, d);
            if (lane >= d) incl += t;
        }
        int excl = incl - s;
        #pragma unroll
        for (int u = 0; u < 10; u++) offs[base + u] = excl + loc[u];
    }
    __syncthreads();
    for (int c = 0; c < 40; c++) {
        int i = c * 1024 + tid;
        bool f = (bid[i] == g);
        unsigned long long m = __ballot(f);
        unsigned long long below = m & ((lane == 63) ? 0x7FFFFFFFFFFFFFFFull
                                                     : ((1ull << lane) - 1ull));
        if (f) {
            int pos = offs[c * 16 + w] + __popcll(below);
            grp[g * GSZ + pos] = i;
            ids[pos] = i;
        }
    }
    __syncthreads();

    // -------- phase B: gather (8 passes of 256 points; serial-fmaf norm order) --------
    for (int pass = 0; pass < 8; pass++) {
        const int q0 = pass * 256;
        for (int s = tid; s < 256 * 64; s += 1024) {
            int q = s >> 6, d = s & 63;
            tile[q][d] = (d < 63) ? x[(size_t)ids[q0 + q] * 90 + d] : 0.f;
        }
        __syncthreads();
        if (tid < 256) {
            float a = 0.f;
            #pragma unroll
            for (int d = 0; d < 63; d++) a = fmaf(tile[tid][d], tile[tid][d], a);
            cn[g * GSZ + q0 + tid] = a;
        }
        for (int s = tid; s < 256 * 32; s += 1024) {
            int q = s >> 5, dp = (s & 31) << 1;
            float v0 = tile[q][dp], v1 = tile[q][dp + 1];
            unsigned short h0 = bf16rne(v0), h1 = bf16rne(v1);
            unsigned short l0 = bf16rne(v0 - bf2f(h0)), l1 = bf16rne(v1 - bf2f(h1));
            size_t pt = (size_t)g * GSZ + q0 + q;
            ((unsigned int*)xbh)[pt * 32 + (dp >> 1)] = (unsigned int)h0 | ((unsigned int)h1 << 16);
            ((unsigned int*)xbl)[pt * 32 + (dp >> 1)] = (unsigned int)l0 | ((unsigned int)l1 << 16);
        }
        __syncthreads();
    }
}

// ---------------- fused trunk layer helper (fp16 2-MFMA split) ----------------
template<int KCH, int KCX, int OUTMODE>   // 0: relu->LDS; 2: no relu->LDS (feat)
__device__ __forceinline__ void mlayer64(_Float16 (*Hh)[264], _Float16 (*Hl)[264],
    int rowbase, const float* __restrict__ x, const _Float16* __restrict__ wl,
    const float* __restrict__ bias, int lane, int wave)
{
    const int r31 = lane & 31, g = lane >> 5;
    constexpr int KC = KCH + KCX;
    const int ct = wave;
    f32x16 acc0, acc1;
    #pragma unroll
    for (int r = 0; r < 16; r++) { acc0[r] = 0.f; acc1[r] = 0.f; }
    const _Float16* wp = wl + (size_t)ct * KC * 512 + lane * 8;
    #pragma unroll
    for (int kc = 0; kc < KCH; kc++) {
        half8 ah0 = *(const half8*)&Hh[r31][kc * 16 + g * 8];
        half8 al0 = *(const half8*)&Hl[r31][kc * 16 + g * 8];
        half8 ah1 = *(const half8*)&Hh[32 + r31][kc * 16 + g * 8];
        half8 al1 = *(const half8*)&Hl[32 + r31][kc * 16 + g * 8];
        half8 b = *(const half8*)(wp + kc * 512);
        acc0 = __builtin_amdgcn_mfma_f32_32x32x16_f16(ah0, b, acc0, 0, 0, 0);
        acc1 = __builtin_amdgcn_mfma_f32_32x32x16_f16(ah1, b, acc1, 0, 0, 0);
        acc0 = __builtin_amdgcn_mfma_f32_32x32x16_f16(al0, b, acc0, 0, 0, 0);
        acc1 = __builtin_amdgcn_mfma_f32_32x32x16_f16(al1, b, acc1, 0, 0, 0);
    }
    #pragma unroll
    for (int t = 0; t < KCX; t++) {
        const int kc = KCH + t;
        float v0[8], v1[8];
        #pragma unroll
        for (int j = 0; j < 8; j++) {
            int kx = t * 16 + g * 8 + j;
            v0[j] = (kx < 63) ? x[(size_t)(rowbase + r31) * 90 + kx] : 0.f;
            v1[j] = (kx < 63) ? x[(size_t)(rowbase + 32 + r31) * 90 + kx] : 0.f;
        }
        half8 xh0, xl0, xh1, xl1;
        splitf16(v0, xh0, xl0);
        splitf16(v1, xh1, xl1);
        half8 b = *(const half8*)(wp + kc * 512);
        acc0 = __builtin_amdgcn_mfma_f32_32x32x16_f16(xh0, b, acc0, 0, 0, 0);
        acc1 = __builtin_amdgcn_mfma_f32_32x32x16_f16(xh1, b, acc1, 0, 0, 0);
        acc0 = __builtin_amdgcn_mfma_f32_32x32x16_f16(xl0, b, acc0, 0, 0, 0);
        acc1 = __builtin_amdgcn_mfma_f32_32x32x16_f16(xl1, b, acc1, 0, 0, 0);
    }
    const float bv = bias[ct * 32 + r31];
    __syncthreads();
    #pragma unroll
    for (int r = 0; r < 16; r++) {
        int row = (r & 3) + 8 * (r >> 2) + 4 * g;
        float v0 = acc0[r] + bv;
        float v1 = acc1[r] + bv;
        if (OUTMODE == 0) { v0 = fmaxf(v0, 0.f); v1 = fmaxf(v1, 0.f); }
        _Float16 h0 = (_Float16)v0, h1 = (_Float16)v1;
        Hh[row][ct * 32 + r31] = h0;
        Hl[row][ct * 32 + r31] = (_Float16)(v0 - (float)h0);
        Hh[32 + row][ct * 32 + r31] = h1;
        Hl[32 + row][ct * 32 + r31] = (_Float16)(v1 - (float)h1);
    }
    __syncthreads();
}

// ---------------- mega kernel: trunk+pq1 [0,640) | kNN-mfma [640,1920), 512 thr ----------------
__global__ __launch_bounds__(512, 4) void k_main(const float* __restrict__ x,
    const _Float16* __restrict__ wfrag,
    const float* __restrict__ b0, const float* __restrict__ bmid,
    const float* __restrict__ bskip, const float* __restrict__ bfin,
    const float* __restrict__ wsig, const float* __restrict__ bsig,
    const _Float16* __restrict__ wfpq1, float* __restrict__ PQ,
    float* __restrict__ out,
    const unsigned short* __restrict__ xbh, const unsigned short* __restrict__ xbl,
    const float* __restrict__ cn, unsigned long long* __restrict__ pkey)
{
    __shared__ union SM {
        struct { _Float16 Hh[64][264]; _Float16 Hl[64][264];
                 _Float16 Dh[64][40];  _Float16 Dl[64][40]; } t;
        char knn[2][16384];
    } sm;
    const int tid = threadIdx.x;
    const int lane = tid & 63;
    const int wave = tid >> 6;
    const int r31 = lane & 31, g = lane >> 5;

    if (blockIdx.x < 640) {
        const int rowbase = blockIdx.x * 64;
        _Float16 (*Hh)[264] = sm.t.Hh;
        _Float16 (*Hl)[264] = sm.t.Hl;
        for (int s = tid; s < 64 * 32; s += 512) {
            int r = s >> 5, d = s & 31;
            float v = (d < 27) ? x[(size_t)(rowbase + r) * 90 + 63 + d] : 0.f;
            _Float16 h = (_Float16)v;
            sm.t.Dh[r][d] = h;
            sm.t.Dl[r][d] = (_Float16)(v - (float)h);
        }
        const _Float16* W = wfrag;
        mlayer64<0, 4, 0>(Hh, Hl, rowbase, x, W + (size_t)0   * 4096, b0,          lane, wave);
        mlayer64<16,0, 0>(Hh, Hl, rowbase, x, W + (size_t)4   * 4096, bmid + 0,    lane, wave);
        mlayer64<16,0, 0>(Hh, Hl, rowbase, x, W + (size_t)20  * 4096, bmid + 256,  lane, wave);
        mlayer64<16,0, 0>(Hh, Hl, rowbase, x, W + (size_t)36  * 4096, bmid + 512,  lane, wave);
        mlayer64<16,4, 0>(Hh, Hl, rowbase, x, W + (size_t)52  * 4096, bskip,       lane, wave);
        mlayer64<16,0, 0>(Hh, Hl, rowbase, x, W + (size_t)72  * 4096, bmid + 768,  lane, wave);
        mlayer64<16,0, 0>(Hh, Hl, rowbase, x, W + (size_t)88  * 4096, bmid + 1024, lane, wave);
        mlayer64<16,0, 0>(Hh, Hl, rowbase, x, W + (size_t)104 * 4096, bmid + 1280, lane, wave);
        if (wave < 2) {
            const int row = wave * 32 + r31;
            float s = 0.f;
            #pragma unroll
            for (int kk = 0; kk < 32; kk++) {
                half4 hh = *(const half4*)&Hh[row][g * 128 + kk * 4];
                half4 hl = *(const half4*)&Hl[row][g * 128 + kk * 4];
                float4 wv = *(const float4*)&wsig[g * 128 + kk * 4];
                s = fmaf((float)hh[0] + (float)hl[0], wv.x, s);
                s = fmaf((float)hh[1] + (float)hl[1], wv.y, s);
                s = fmaf((float)hh[2] + (float)hl[2], wv.z, s);
                s = fmaf((float)hh[3] + (float)hl[3], wv.w, s);
            }
            s += __shfl_xor(s, 32);
            if (lane < 32) out[(size_t)(rowbase + row) * 4 + 3] = s + bsig[0];
        }
        mlayer64<16,0, 2>(Hh, Hl, rowbase, x, W + (size_t)120 * 4096, bfin, lane, wave);
        {
            const int ct = wave;
            f32x16 p0, p1;
            #pragma unroll
            for (int r = 0; r < 16; r++) { p0[r] = 0.f; p1[r] = 0.f; }
            const _Float16* wp = wfpq1 + (size_t)ct * 18 * 512 + lane * 8;
            #pragma unroll
            for (int kc = 0; kc < 16; kc++) {
                half8 ah0 = *(const half8*)&Hh[r31][kc * 16 + g * 8];
                half8 al0 = *(const half8*)&Hl[r31][kc * 16 + g * 8];
                half8 ah1 = *(const half8*)&Hh[32 + r31][kc * 16 + g * 8];
                half8 al1 = *(const half8*)&Hl[32 + r31][kc * 16 + g * 8];
                half8 b = *(const half8*)(wp + kc * 512);
                p0 = __builtin_amdgcn_mfma_f32_32x32x16_f16(ah0, b, p0, 0, 0, 0);
                p1 = __builtin_amdgcn_mfma_f32_32x32x16_f16(ah1, b, p1, 0, 0, 0);
                p0 = __builtin_amdgcn_mfma_f32_32x32x16_f16(al0, b, p0, 0, 0, 0);
                p1 = __builtin_amdgcn_mfma_f32_32x32x16_f16(al1, b, p1, 0, 0, 0);
            }
            #pragma unroll
            for (int kc = 16; kc < 18; kc++) {
                const int dc = (kc - 16) * 16 + g * 8;
                half8 ah0 = *(const half8*)&sm.t.Dh[r31][dc];
                half8 al0 = *(const half8*)&sm.t.Dl[r31][dc];
                half8 ah1 = *(const half8*)&sm.t.Dh[32 + r31][dc];
                half8 al1 = *(const half8*)&sm.t.Dl[32 + r31][dc];
                half8 b = *(const half8*)(wp + kc * 512);
                p0 = __builtin_amdgcn_mfma_f32_32x32x16_f16(ah0, b, p0, 0, 0, 0);
                p1 = __builtin_amdgcn_mfma_f32_32x32x16_f16(ah1, b, p1, 0, 0, 0);
                p0 = __builtin_amdgcn_mfma_f32_32x32x16_f16(al0, b, p0, 0, 0, 0);
                p1 = __builtin_amdgcn_mfma_f32_32x32x16_f16(al1, b, p1, 0, 0, 0);
            }
            #pragma unroll
            for (int r = 0; r < 16; r++) {
                int row = (r & 3) + 8 * (r >> 2) + 4 * g;
                PQ[(size_t)(rowbase + row) * 256 + ct * 32 + r31] = p0[r];
                PQ[(size_t)(rowbase + 32 + row) * 256 + ct * 32 + r31] = p1[r];
            }
        }
    } else {
        const int bb = blockIdx.x - 640;
        const int gg = bb >> 6;
        const int rem = bb & 63;
        const int part = rem >> 4;
        const int qx = rem & 15;
        const int qt0 = qx * 128 + wave * 16;
        const size_t gbase = (size_t)gg * GSZ;
        const int lp = lane & 15;
        const int kgrp = lane >> 4;
        const int kg = kgrp << 3;
        char (*cbuf)[16384] = sm.knn;

        const size_t qb = (gbase + qt0 + lp) * 64;
        short8 ah0 = *(const short8*)(xbh + qb + kg);
        short8 ah1 = *(const short8*)(xbh + qb + 32 + kg);
        short8 al0 = *(const short8*)(xbl + qb + kg);
        short8 al1 = *(const short8*)(xbl + qb + 32 + kg);

        const int qp0 = qt0 + (kgrp << 2);

        unsigned int K00 = ~0u, I00 = 0, K01 = ~0u, I01 = 0, K02 = ~0u, I02 = 0;
        unsigned int K10 = ~0u, I10 = 0, K11 = ~0u, I11 = 0, K12 = ~0u, I12 = 0;
        unsigned int K20 = ~0u, I20 = 0, K21 = ~0u, I21 = 0, K22 = ~0u, I22 = 0;
        unsigned int K30 = ~0u, I30 = 0, K31 = ~0u, I31 = 0, K32 = ~0u, I32 = 0;

        const int cbeg = part * (GSZ / CPART);

        short8 st0, st1;
        {
            size_t cb = (gbase + cbeg + lane) * 64;
            st0 = *(const short8*)(xbh + cb + wave * 8);
            st1 = *(const short8*)(xbl + cb + wave * 8);
        }
        *(short8*)&cbuf[0][(wave << 10) + (lane << 4)] = st0;
        *(short8*)&cbuf[0][((8 + wave) << 10) + (lane << 4)] = st1;

        for (int ch = 0; ch < 8; ch++) {
            const int cur = ch & 1;
            __syncthreads();
            if (ch < 7) {
                size_t cb = (gbase + cbeg + (ch + 1) * 64 + lane) * 64;
                st0 = *(const short8*)(xbh + cb + wave * 8);
                st1 = *(const short8*)(xbl + cb + wave * 8);
            }
            const int cc0 = cbeg + ch * 64;
            #pragma unroll
            for (int ct = 0; ct < 4; ct++) {
                const int coff = ((ct * 16 + lp) << 4);
                short8 bh0 = *(const short8*)&cbuf[cur][((kgrp)      << 10) + coff];
                short8 bh1 = *(const short8*)&cbuf[cur][((4 + kgrp)  << 10) + coff];
                short8 bl0 = *(const short8*)&cbuf[cur][((8 + kgrp)  << 10) + coff];
                short8 bl1 = *(const short8*)&cbuf[cur][((12 + kgrp) << 10) + coff];
                f32x4 acc = {0.f, 0.f, 0.f, 0.f};
                acc = __builtin_amdgcn_mfma_f32_16x16x32_bf16(ah0, bh0, acc, 0, 0, 0);
                acc = __builtin_amdgcn_mfma_f32_16x16x32_bf16(ah1, bh1, acc, 0, 0, 0);
                acc = __builtin_amdgcn_mfma_f32_16x16x32_bf16(al0, bh0, acc, 0, 0, 0);
                acc = __builtin_amdgcn_mfma_f32_16x16x32_bf16(al1, bh1, acc, 0, 0, 0);
                acc = __builtin_amdgcn_mfma_f32_16x16x32_bf16(ah0, bl0, acc, 0, 0, 0);
                acc = __builtin_amdgcn_mfma_f32_16x16x32_bf16(ah1, bl1, acc, 0, 0, 0);
                const float cnv = cn[gbase + cc0 + ct * 16 + lp];
                const int cpos = cc0 + ct * 16 + lp;
                const unsigned int ci = (unsigned int)cpos;
                {
                    unsigned int k = fkey(fmaf(-2.f, acc[0], cnv));
                    k = (cpos == qp0 + 0) ? 0xFFFFFFFFu : k;
                    ins3p(k, ci, K00, I00, K01, I01, K02, I02);
                }
                {
                    unsigned int k = fkey(fmaf(-2.f, acc[1], cnv));
                    k = (cpos == qp0 + 1) ? 0xFFFFFFFFu : k;
                    ins3p(k, ci, K10, I10, K11, I11, K12, I12);
                }
                {
                    unsigned int k = fkey(fmaf(-2.f, acc[2], cnv));
                    k = (cpos == qp0 + 2) ? 0xFFFFFFFFu : k;
                    ins3p(k, ci, K20, I20, K21, I21, K22, I22);
                }
                {
                    unsigned int k = fkey(fmaf(-2.f, acc[3], cnv));
                    k = (cpos == qp0 + 3) ? 0xFFFFFFFFu : k;
                    ins3p(k, ci, K30, I30, K31, I31, K32, I32);
                }
            }
            if (ch < 7) {
                *(short8*)&cbuf[cur ^ 1][(wave << 10) + (lane << 4)] = st0;
                *(short8*)&cbuf[cur ^ 1][((8 + wave) << 10) + (lane << 4)] = st1;
            }
        }

        mergerow(K00, I00, K01, I01, K02, I02);
        mergerow(K10, I10, K11, I11, K12, I12);
        mergerow(K20, I20, K21, I21, K22, I22);
        mergerow(K30, I30, K31, I31, K32, I32);

        if (lp == 0) {
            size_t ob = (gbase + (size_t)qp0) * (CPART * 3) + part * 3;
            pkey[ob + 0]  = ((unsigned long long)K00 << 32) | I00;
            pkey[ob + 1]  = ((unsigned long long)K01 << 32) | I01;
            pkey[ob + 2]  = ((unsigned long long)K02 << 32) | I02;
            pkey[ob + 12] = ((unsigned long long)K10 << 32) | I10;
            pkey[ob + 13] = ((unsigned long long)K11 << 32) | I11;
            pkey[ob + 14] = ((unsigned long long)K12 << 32) | I12;
            pkey[ob + 24] = ((unsigned long long)K20 << 32) | I20;
            pkey[ob + 25] = ((unsigned long long)K21 << 32) | I21;
            pkey[ob + 26] = ((unsigned long long)K22 << 32) | I22;
            pkey[ob + 36] = ((unsigned long long)K30 << 32) | I30;
            pkey[ob + 37] = ((unsigned long long)K31 << 32) | I31;
            pkey[ob + 38] = ((unsigned long long)K32 << 32) | I32;
        }
    }
}

// ---------------- kNN merge ----------------
__device__ __forceinline__ void ins3u(unsigned long long k,
    unsigned long long& k0, unsigned long long& k1, unsigned long long& k2)
{
    if (k < k0)      { k2 = k1; k1 = k0; k0 = k; }
    else if (k < k1) { k2 = k1; k1 = k; }
    else if (k < k2) { k2 = k; }
}

__global__ void k_knn_merge(const unsigned long long* __restrict__ pkey,
                            const int* __restrict__ grp, int* __restrict__ nbr)
{
    int t = blockIdx.x * 256 + threadIdx.x;
    if (t >= NGRP * GSZ) return;
    int g = t >> 11;
    unsigned long long k0 = ~0ull, k1 = ~0ull, k2 = ~0ull;
    const unsigned long long* pk = pkey + (size_t)t * (CPART * 3);
    #pragma unroll
    for (int r = 0; r < CPART * 3; r++) ins3u(pk[r], k0, k1, k2);
    int qi = grp[t];
    nbr[(size_t)qi * 3 + 0] = grp[(g << 11) + (int)(k0 & 0xFFFFFFFFull)];
    nbr[(size_t)qi * 3 + 1] = grp[(g << 11) + (int)(k1 & 0xFFFFFFFFull)];
    nbr[(size_t)qi * 3 + 2] = grp[(g << 11) + (int)(k2 & 0xFFFFFFFFull)];
}

// ---------------- edge conv via MFMA (+ fused pq2 when RGB==0) ----------------
template<int RGB>
__global__ __launch_bounds__(256) void k_edge_mfma(const float* __restrict__ PQ,
    const float* __restrict__ b1, const _Float16* __restrict__ wf2,
    const float* __restrict__ b2, const int* __restrict__ nbr,
    const _Float16* __restrict__ wfpq2, float* __restrict__ pqout,
    const float* __restrict__ wrgb, const float* __restrict__ brgb,
    float* __restrict__ out)
{
    __shared__ _Float16 Hh[128][136];
    __shared__ _Float16 Hl[128][136];
    const int tid = threadIdx.x;
    const int lane = tid & 63, wave = tid >> 6;
    const int r31 = lane & 31, g = lane >> 5;
    const int n0 = blockIdx.x * 32;

    for (int s = tid; s < 128 * 32; s += 256) {
        int e = s >> 5, c4 = (s & 31) << 2;
        int n = e >> 2, jj = e & 3;
        half4 zh = {(_Float16)0.f, (_Float16)0.f, (_Float16)0.f, (_Float16)0.f};
        if (jj < 3) {
            int i = n0 + n;
            int j = nbr[(size_t)i * 3 + jj];
            float4 p  = *(const float4*)&PQ[(size_t)i * 256 + c4];
            float4 qi = *(const float4*)&PQ[(size_t)i * 256 + 128 + c4];
            float4 qj = *(const float4*)&PQ[(size_t)j * 256 + 128 + c4];
            float4 bv = *(const float4*)&b1[c4];
            float v[4];
            v[0] = fmaxf(p.x + bv.x + qj.x - qi.x, 0.f);
            v[1] = fmaxf(p.y + bv.y + qj.y - qi.y, 0.f);
            v[2] = fmaxf(p.z + bv.z + qj.z - qi.z, 0.f);
            v[3] = fmaxf(p.w + bv.w + qj.w - qi.w, 0.f);
            half4 hh, hl;
            #pragma unroll
            for (int u = 0; u < 4; u++) {
                _Float16 h = (_Float16)v[u];
                hh[u] = h;
                hl[u] = (_Float16)(v[u] - (float)h);
            }
            *(half4*)&Hh[e][c4] = hh;
            *(half4*)&Hl[e][c4] = hl;
        } else {
            *(half4*)&Hh[e][c4] = zh;
            *(half4*)&Hl[e][c4] = zh;
        }
    }
    __syncthreads();

    const int ct = wave;
    f32x16 a0, a1, a2, a3;
    #pragma unroll
    for (int r = 0; r < 16; r++) { a0[r] = 0.f; a1[r] = 0.f; a2[r] = 0.f; a3[r] = 0.f; }
    const _Float16* wp = wf2 + (size_t)ct * 8 * 512 + lane * 8;
    #pragma unroll
    for (int kc = 0; kc < 8; kc++) {
        half8 b = *(const half8*)(wp + kc * 512);
        half8 h0 = *(const half8*)&Hh[r31][kc * 16 + g * 8];
        half8 l0 = *(const half8*)&Hl[r31][kc * 16 + g * 8];
        a0 = __builtin_amdgcn_mfma_f32_32x32x16_f16(h0, b, a0, 0, 0, 0);
        a0 = __builtin_amdgcn_mfma_f32_32x32x16_f16(l0, b, a0, 0, 0, 0);
        half8 h1 = *(const half8*)&Hh[32 + r31][kc * 16 + g * 8];
        half8 l1 = *(const half8*)&Hl[32 + r31][kc * 16 + g * 8];
        a1 = __builtin_amdgcn_mfma_f32_32x32x16_f16(h1, b, a1, 0, 0, 0);
        a1 = __builtin_amdgcn_mfma_f32_32x32x16_f16(l1, b, a1, 0, 0, 0);
        half8 h2 = *(const half8*)&Hh[64 + r31][kc * 16 + g * 8];
        half8 l2 = *(const half8*)&Hl[64 + r31][kc * 16 + g * 8];
        a2 = __builtin_amdgcn_mfma_f32_32x32x16_f16(h2, b, a2, 0, 0, 0);
        a2 = __builtin_amdgcn_mfma_f32_32x32x16_f16(l2, b, a2, 0, 0, 0);
        half8 h3 = *(const half8*)&Hh[96 + r31][kc * 16 + g * 8];
        half8 l3 = *(const half8*)&Hl[96 + r31][kc * 16 + g * 8];
        a3 = __builtin_amdgcn_mfma_f32_32x32x16_f16(h3, b, a3, 0, 0, 0);
        a3 = __builtin_amdgcn_mfma_f32_32x32x16_f16(l3, b, a3, 0, 0, 0);
    }
    const float bv = b2[ct * 32 + r31];
    const int col = ct * 32 + r31;

    if (!RGB) {
        __syncthreads();
        #pragma unroll
        for (int q = 0; q < 4; q++) {
            float s0 = fmaxf(a0[4*q] + bv, 0.f) + fmaxf(a0[4*q+1] + bv, 0.f) + fmaxf(a0[4*q+2] + bv, 0.f);
            float s1 = fmaxf(a1[4*q] + bv, 0.f) + fmaxf(a1[4*q+1] + bv, 0.f) + fmaxf(a1[4*q+2] + bv, 0.f);
            float s2 = fmaxf(a2[4*q] + bv, 0.f) + fmaxf(a2[4*q+1] + bv, 0.f) + fmaxf(a2[4*q+2] + bv, 0.f);
            float s3 = fmaxf(a3[4*q] + bv, 0.f) + fmaxf(a3[4*q+1] + bv, 0.f) + fmaxf(a3[4*q+2] + bv, 0.f);
            int nq = 2 * q + g;
            float v0 = s0 * (1.f / 3.f), v1 = s1 * (1.f / 3.f);
            float v2 = s2 * (1.f / 3.f), v3 = s3 * (1.f / 3.f);
            _Float16 h0 = (_Float16)v0, h1 = (_Float16)v1, h2 = (_Float16)v2, h3 = (_Float16)v3;
            Hh[0  + nq][col] = h0; Hl[0  + nq][col] = (_Float16)(v0 - (float)h0);
            Hh[8  + nq][col] = h1; Hl[8  + nq][col] = (_Float16)(v1 - (float)h1);
            Hh[16 + nq][col] = h2; Hl[16 + nq][col] = (_Float16)(v2 - (float)h2);
            Hh[24 + nq][col] = h3; Hl[24 + nq][col] = (_Float16)(v3 - (float)h3);
        }
        __syncthreads();
        const int ct0 = wave * 2;
        f32x16 p0, p1;
        #pragma unroll
        for (int r = 0; r < 16; r++) { p0[r] = 0.f; p1[r] = 0.f; }
        const _Float16* wq0 = wfpq2 + (size_t)ct0 * 8 * 512 + lane * 8;
        const _Float16* wq1 = wq0 + (size_t)8 * 512;
        #pragma unroll
        for (int kc = 0; kc < 8; kc++) {
            half8 ah = *(const half8*)&Hh[r31][kc * 16 + g * 8];
            half8 al = *(const half8*)&Hl[r31][kc * 16 + g * 8];
            half8 b0v = *(const half8*)(wq0 + kc * 512);
            half8 b1v = *(const half8*)(wq1 + kc * 512);
            p0 = __builtin_amdgcn_mfma_f32_32x32x16_f16(ah, b0v, p0, 0, 0, 0);
            p1 = __builtin_amdgcn_mfma_f32_32x32x16_f16(ah, b1v, p1, 0, 0, 0);
            p0 = __builtin_amdgcn_mfma_f32_32x32x16_f16(al, b0v, p0, 0, 0, 0);
            p1 = __builtin_amdgcn_mfma_f32_32x32x16_f16(al, b1v, p1, 0, 0, 0);
        }
        #pragma unroll
        for (int r = 0; r < 16; r++) {
            int row = (r & 3) + 8 * (r >> 2) + 4 * g;
            pqout[(size_t)(n0 + row) * 256 + ct0 * 32 + r31] = p0[r];
            pqout[(size_t)(n0 + row) * 256 + ct0 * 32 + 32 + r31] = p1[r];
        }
    } else {
        __syncthreads();
        float* d2L = (float*)&Hh[0][0];
        #pragma unroll
        for (int q = 0; q < 4; q++) {
            float s0 = fmaxf(a0[4*q] + bv, 0.f) + fmaxf(a0[4*q+1] + bv, 0.f) + fmaxf(a0[4*q+2] + bv, 0.f);
            float s1 = fmaxf(a1[4*q] + bv, 0.f) + fmaxf(a1[4*q+1] + bv, 0.f) + fmaxf(a1[4*q+2] + bv, 0.f);
            float s2 = fmaxf(a2[4*q] + bv, 0.f) + fmaxf(a2[4*q+1] + bv, 0.f) + fmaxf(a2[4*q+2] + bv, 0.f);
            float s3 = fmaxf(a3[4*q] + bv, 0.f) + fmaxf(a3[4*q+1] + bv, 0.f) + fmaxf(a3[4*q+2] + bv, 0.f);
            int nq = 2 * q + g;
            d2L[(0  + nq) * 132 + col] = s0 * (1.f / 3.f);
            d2L[(8  + nq) * 132 + col] = s1 * (1.f / 3.f);
            d2L[(16 + nq) * 132 + col] = s2 * (1.f / 3.f);
            d2L[(24 + nq) * 132 + col] = s3 * (1.f / 3.f);
        }
        __syncthreads();
        if (tid < 96) {
            int n = tid / 3, ch = tid - 3 * (tid / 3);
            float s = brgb[ch];
            for (int k = 0; k < 128; k++) s = fmaf(d2L[n * 132 + k], wrgb[k * 3 + ch], s);
            out[(size_t)(n0 + n) * 4 + ch] = 1.f / (1.f + expf(-s));
        }
    }
}

// ---------------- launch ----------------
extern "C" void kernel_launch(void* const* d_in, const int* in_sizes, int n_in,
                              void* d_out, int out_size, void* d_ws, size_t ws_size,
                              hipStream_t stream)
{
    const float* x     = (const float*)d_in[0];
    const int*   bid   = (const int*)d_in[1];
    const float* w0    = (const float*)d_in[2];
    const float* b0    = (const float*)d_in[3];
    const float* wmid  = (const float*)d_in[4];
    const float* bmid  = (const float*)d_in[5];
    const float* wskip = (const float*)d_in[6];
    const float* bskip = (const float*)d_in[7];
    const float* wfin  = (const float*)d_in[8];
    const float* bfin  = (const float*)d_in[9];
    const float* wsig  = (const float*)d_in[10];
    const float* bsig  = (const float*)d_in[11];
    const float* e1w1  = (const float*)d_in[12];
    const float* e1b1  = (const float*)d_in[13];
    const float* e1w2  = (const float*)d_in[14];
    const float* e1b2  = (const float*)d_in[15];
    const float* e2w1  = (const float*)d_in[16];
    const float* e2b1  = (const float*)d_in[17];
    const float* e2w2  = (const float*)d_in[18];
    const float* e2b2  = (const float*)d_in[19];
    const float* wrgb  = (const float*)d_in[20];
    const float* brgb  = (const float*)d_in[21];
    float* out = (float*)d_out;

    char* ws = (char*)d_ws;
    int* grp = (int*)(ws + 256);
    int* nbr = (int*)(ws + 164096);
    _Float16* wfpq1 = (_Float16*)(ws + 655616);
    _Float16* wfpq2 = (_Float16*)(ws + 950528);
    _Float16* wfe1  = (_Float16*)(ws + 1081600);
    _Float16* wfe2  = (_Float16*)(ws + 1147136);
    float* bufA = (float*)(ws + (2 << 20));
    float* bufB = bufA + (size_t)B_TOTAL * 256;

    unsigned short* xbh = (unsigned short*)bufA;
    unsigned short* xbl = xbh + (size_t)B_TOTAL * 64;
    float* cn   = (float*)(xbl + (size_t)B_TOTAL * 64);
    unsigned long long* pkey = (unsigned long long*)(cn + B_TOTAL);
    _Float16* wfrag = (_Float16*)((char*)bufA + ((size_t)20 << 20));
    float* PQ  = bufB;
    float* PQ2 = bufA;

    k_front<<<700, 1024, 0, stream>>>(bid, grp, x, xbh, xbl, cn,
                                      w0, wmid, wskip, wfin, wfrag,
                                      e1w1, wfpq1, e2w1, wfpq2,
                                      e1w2, wfe1, e2w2, wfe2);
    k_main<<<640 + 1280, 512, 0, stream>>>(x, wfrag, b0, bmid, bskip, bfin,
                                           wsig, bsig, wfpq1, PQ, out,
                                           xbh, xbl, cn, pkey);
    k_knn_merge<<<(NGRP * GSZ + 255) / 256, 256, 0, stream>>>(pkey, grp, nbr);
    k_edge_mfma<0><<<B_TOTAL / 32, 256, 0, stream>>>(PQ, e1b1, wfe1, e1b2, nbr,
                                                     wfpq2, PQ2, nullptr, nullptr, nullptr);
    k_edge_mfma<1><<<B_TOTAL / 32, 256, 0, stream>>>(PQ2, e2b1, wfe2, e2b2, nbr,
                                                     nullptr, nullptr, wrgb, brgb, out);
}

// Round 21
// 320.712 us; speedup vs baseline: 1.1151x; 1.1151x over previous
//
#include <hip/hip_runtime.h>
#include <hip/hip_bf16.h>
#include <math.h>

#define B_TOTAL 40960
#define NGRP 20
#define GSZ 2048
#define CPART 4

typedef short short8 __attribute__((ext_vector_type(8)));
typedef float f32x4 __attribute__((ext_vector_type(4)));
typedef float f32x16 __attribute__((ext_vector_type(16)));
typedef _Float16 half8 __attribute__((ext_vector_type(8)));
typedef _Float16 half4 __attribute__((ext_vector_type(4)));

// ---------------- bf16 helpers (kNN path) ----------------
__device__ __forceinline__ unsigned short bf16rne(float v)
{
    unsigned int u = __float_as_uint(v);
    unsigned int r = (u + 0x7FFFu + ((u >> 16) & 1u)) >> 16;
    return (unsigned short)r;
}

__device__ __forceinline__ float bf2f(unsigned short h)
{
    return __uint_as_float((unsigned int)h << 16);
}

// ---------------- fp16 split helper (MLP path) ----------------
__device__ __forceinline__ void splitf16(const float* v, half8& hi, half8& lo)
{
    #pragma unroll
    for (int j = 0; j < 8; j++) {
        _Float16 h = (_Float16)v[j];
        hi[j] = h;
        lo[j] = (_Float16)(v[j] - (float)h);
    }
}

// ordered-float key
__device__ __forceinline__ unsigned int fkey(float f)
{
    unsigned int u = __float_as_uint(f);
    unsigned int m = (unsigned int)((int)u >> 31) | 0x80000000u;
    return u ^ m;
}

__device__ __forceinline__ void ins3p(unsigned int k, unsigned int i,
    unsigned int& k0, unsigned int& i0, unsigned int& k1, unsigned int& i1,
    unsigned int& k2, unsigned int& i2)
{
    bool c0 = k < k0;
    unsigned int tk = c0 ? k0 : k, ti = c0 ? i0 : i;
    k0 = c0 ? k : k0;  i0 = c0 ? i : i0;
    bool c1 = tk < k1;
    unsigned int sk = c1 ? k1 : tk, si = c1 ? i1 : ti;
    k1 = c1 ? tk : k1; i1 = c1 ? ti : i1;
    bool c2 = sk < k2;
    k2 = c2 ? sk : k2; i2 = c2 ? si : i2;
}

__device__ __forceinline__ void mergerow(unsigned int& k0, unsigned int& i0,
    unsigned int& k1, unsigned int& i1, unsigned int& k2, unsigned int& i2)
{
    #pragma unroll
    for (int m = 1; m <= 8; m <<= 1) {
        unsigned int ok0 = (unsigned int)__shfl_xor((int)k0, m);
        unsigned int oi0 = (unsigned int)__shfl_xor((int)i0, m);
        unsigned int ok1 = (unsigned int)__shfl_xor((int)k1, m);
        unsigned int oi1 = (unsigned int)__shfl_xor((int)i1, m);
        unsigned int ok2 = (unsigned int)__shfl_xor((int)k2, m);
        unsigned int oi2 = (unsigned int)__shfl_xor((int)i2, m);
        ins3p(ok0, oi0, k0, i0, k1, i1, k2, i2);
        ins3p(ok1, oi1, k0, i0, k1, i1, k2, i2);
        ins3p(ok2, oi2, k0, i0, k1, i1, k2, i2);
    }
}

// ---------------- deterministic scatter: ballot compaction, ascending order ----------------
__global__ __launch_bounds__(1024) void k_scatter_det(const int* __restrict__ bid,
                                                      int* __restrict__ grp)
{
    __shared__ int cnts[640];   // [chunk 0..39][wave 0..15]
    __shared__ int offs[640];
    const int tid = threadIdx.x;
    const int w = tid >> 6, lane = tid & 63;
    const int g = blockIdx.x;
    for (int c = 0; c < 40; c++) {
        int i = c * 1024 + tid;
        unsigned long long m = __ballot(bid[i] == g);
        if (lane == 0) cnts[c * 16 + w] = __popcll(m);
    }
    __syncthreads();
    if (w == 0) {
        int base = lane * 10;
        int loc[10];
        int s = 0;
        #pragma unroll
        for (int u = 0; u < 10; u++) { loc[u] = s; s += cnts[base + u]; }
        int incl = s;
        #pragma unroll
        for (int d = 1; d < 64; d <<= 1) {
            int t = __shfl_up(incl, d);
            if (lane >= d) incl += t;
        }
        int excl = incl - s;
        #pragma unroll
        for (int u = 0; u < 10; u++) offs[base + u] = excl + loc[u];
    }
    __syncthreads();
    for (int c = 0; c < 40; c++) {
        int i = c * 1024 + tid;
        bool f = (bid[i] == g);
        unsigned long long m = __ballot(f);
        unsigned long long below = m & ((lane == 63) ? 0x7FFFFFFFFFFFFFFFull
                                                     : ((1ull << lane) - 1ull));
        if (f) grp[g * GSZ + offs[c * 16 + w] + __popcll(below)] = i;
    }
}

// ---------------- fused prep: weight preps only ----------------
__device__ __forceinline__ void do_wprep_trunk(int t, const float* __restrict__ w0,
    const float* __restrict__ wmid, const float* __restrict__ wskip,
    const float* __restrict__ wfin, _Float16* __restrict__ wfrag)
{
    const int CUMa[10] = {0,4,20,36,52,72,88,104,120,136};
    const int KCa[9]   = {4,16,16,16,20,16,16,16,16};
    int q = t >> 12;
    int L = 0;
    #pragma unroll
    for (int i = 0; i < 9; i++) if (q >= CUMa[i + 1]) L = i + 1;
    int cum = 0, kcn = 16;
    #pragma unroll
    for (int i = 0; i < 9; i++) if (L == i) { cum = CUMa[i]; kcn = KCa[i]; }
    int u = t - (cum << 12);
    int j = u & 7, lane = (u >> 3) & 63;
    int ckk = u >> 9;
    int kc = ckk % kcn, ct = ckk / kcn;
    int col = ct * 32 + (lane & 31);
    int k = kc * 16 + ((lane >> 5) << 3) + j;
    float w;
    if (L == 0)      w = (k < 63)  ? w0[k * 256 + col] : 0.f;
    else if (L == 4) w = (k < 256) ? wskip[(63 + k) * 256 + col]
                       : (k < 319) ? wskip[(k - 256) * 256 + col] : 0.f;
    else if (L == 8) w = wfin[k * 256 + col];
    else {
        int m = (L <= 3) ? (L - 1) : (L - 2);
        w = wmid[(size_t)m * 65536 + k * 256 + col];
    }
    wfrag[((size_t)cum << 12) + (size_t)ckk * 512 + lane * 8 + j] = (_Float16)w;
}

__device__ __forceinline__ void do_wprep_pq(int t, const float* __restrict__ src,
    int K, int KCN, _Float16* __restrict__ dst)
{
    int j = t & 7, lane = (t >> 3) & 63;
    int ckk = t >> 9;
    int kc = ckk % KCN, ct = ckk / KCN;
    int col = ct * 32 + (lane & 31);
    int k = kc * 16 + ((lane >> 5) << 3) + j;
    float w = 0.f;
    if (k < K) w = (col < 128) ? src[(size_t)k * 128 + col]
                               : src[(size_t)(K + k) * 128 + (col - 128)];
    dst[(size_t)ckk * 512 + lane * 8 + j] = (_Float16)w;
}

__device__ __forceinline__ void do_wprep_sq(int t, const float* __restrict__ src,
    _Float16* __restrict__ dst)
{
    int j = t & 7, lane = (t >> 3) & 63;
    int ckk = t >> 9;
    int kc = ckk & 7, ct = ckk >> 3;
    int col = ct * 32 + (lane & 31);
    int k = kc * 16 + ((lane >> 5) << 3) + j;
    dst[(size_t)ckk * 512 + lane * 8 + j] = (_Float16)src[(size_t)k * 128 + col];
}

// block ranges: [0,2176) trunk | [2176,2464) pq1 | [2464,2592) pq2 |
// [2592,2656) e1w2 | [2656,2720) e2w2
__global__ void k_prep(const float* __restrict__ w0, const float* __restrict__ wmid,
                       const float* __restrict__ wskip, const float* __restrict__ wfin,
                       _Float16* __restrict__ wfrag,
                       const float* __restrict__ e1w1, _Float16* __restrict__ wfpq1,
                       const float* __restrict__ e2w1, _Float16* __restrict__ wfpq2,
                       const float* __restrict__ e1w2, _Float16* __restrict__ wfe1,
                       const float* __restrict__ e2w2, _Float16* __restrict__ wfe2)
{
    const int b = blockIdx.x;
    const int tid = threadIdx.x;
    if (b < 2176) {
        do_wprep_trunk(b * 256 + tid, w0, wmid, wskip, wfin, wfrag);
    } else if (b < 2464) {
        do_wprep_pq((b - 2176) * 256 + tid, e1w1, 283, 18, wfpq1);
    } else if (b < 2592) {
        do_wprep_pq((b - 2464) * 256 + tid, e2w1, 128, 8, wfpq2);
    } else if (b < 2656) {
        do_wprep_sq((b - 2592) * 256 + tid, e1w2, wfe1);
    } else {
        do_wprep_sq((b - 2656) * 256 + tid, e2w2, wfe2);
    }
}

// ---------------- kNN stage 1: gather -> packed bf16 hi/lo planes + norms ----------------
__global__ __launch_bounds__(256) void k_gather(const float* __restrict__ x,
    const int* __restrict__ grp, unsigned short* __restrict__ xbh,
    unsigned short* __restrict__ xbl, float* __restrict__ cn)
{
    __shared__ float tile[128][65];
    __shared__ int ids[128];
    const int tid = threadIdx.x;
    const int g = blockIdx.y;
    const int q0 = blockIdx.x * 128;
    if (tid < 128) ids[tid] = grp[g * GSZ + q0 + tid];
    __syncthreads();
    for (int s = tid; s < 128 * 64; s += 256) {
        int q = s >> 6, d = s & 63;
        tile[q][d] = (d < 63) ? x[(size_t)ids[q] * 90 + d] : 0.f;
    }
    __syncthreads();
    if (tid < 128) {
        float a = 0.f;
        #pragma unroll
        for (int d = 0; d < 63; d++) a = fmaf(tile[tid][d], tile[tid][d], a);
        cn[g * GSZ + q0 + tid] = a;
    }
    for (int s = tid; s < 128 * 32; s += 256) {
        int q = s >> 5, dp = (s & 31) << 1;
        float v0 = tile[q][dp], v1 = tile[q][dp + 1];
        unsigned short h0 = bf16rne(v0), h1 = bf16rne(v1);
        unsigned short l0 = bf16rne(v0 - bf2f(h0)), l1 = bf16rne(v1 - bf2f(h1));
        size_t pt = (size_t)g * GSZ + q0 + q;
        ((unsigned int*)xbh)[pt * 32 + (dp >> 1)] = (unsigned int)h0 | ((unsigned int)h1 << 16);
        ((unsigned int*)xbl)[pt * 32 + (dp >> 1)] = (unsigned int)l0 | ((unsigned int)l1 << 16);
    }
}

// ---------------- fused trunk layer helper (fp16 2-MFMA split) ----------------
template<int KCH, int KCX, int OUTMODE>   // 0: relu->LDS; 2: no relu->LDS (feat)
__device__ __forceinline__ void mlayer64(_Float16 (*Hh)[264], _Float16 (*Hl)[264],
    int rowbase, const float* __restrict__ x, const _Float16* __restrict__ wl,
    const float* __restrict__ bias, int lane, int wave)
{
    const int r31 = lane & 31, g = lane >> 5;
    constexpr int KC = KCH + KCX;
    const int ct = wave;
    f32x16 acc0, acc1;
    #pragma unroll
    for (int r = 0; r < 16; r++) { acc0[r] = 0.f; acc1[r] = 0.f; }
    const _Float16* wp = wl + (size_t)ct * KC * 512 + lane * 8;
    #pragma unroll
    for (int kc = 0; kc < KCH; kc++) {
        half8 ah0 = *(const half8*)&Hh[r31][kc * 16 + g * 8];
        half8 al0 = *(const half8*)&Hl[r31][kc * 16 + g * 8];
        half8 ah1 = *(const half8*)&Hh[32 + r31][kc * 16 + g * 8];
        half8 al1 = *(const half8*)&Hl[32 + r31][kc * 16 + g * 8];
        half8 b = *(const half8*)(wp + kc * 512);
        acc0 = __builtin_amdgcn_mfma_f32_32x32x16_f16(ah0, b, acc0, 0, 0, 0);
        acc1 = __builtin_amdgcn_mfma_f32_32x32x16_f16(ah1, b, acc1, 0, 0, 0);
        acc0 = __builtin_amdgcn_mfma_f32_32x32x16_f16(al0, b, acc0, 0, 0, 0);
        acc1 = __builtin_amdgcn_mfma_f32_32x32x16_f16(al1, b, acc1, 0, 0, 0);
    }
    #pragma unroll
    for (int t = 0; t < KCX; t++) {
        const int kc = KCH + t;
        float v0[8], v1[8];
        #pragma unroll
        for (int j = 0; j < 8; j++) {
            int kx = t * 16 + g * 8 + j;
            v0[j] = (kx < 63) ? x[(size_t)(rowbase + r31) * 90 + kx] : 0.f;
            v1[j] = (kx < 63) ? x[(size_t)(rowbase + 32 + r31) * 90 + kx] : 0.f;
        }
        half8 xh0, xl0, xh1, xl1;
        splitf16(v0, xh0, xl0);
        splitf16(v1, xh1, xl1);
        half8 b = *(const half8*)(wp + kc * 512);
        acc0 = __builtin_amdgcn_mfma_f32_32x32x16_f16(xh0, b, acc0, 0, 0, 0);
        acc1 = __builtin_amdgcn_mfma_f32_32x32x16_f16(xh1, b, acc1, 0, 0, 0);
        acc0 = __builtin_amdgcn_mfma_f32_32x32x16_f16(xl0, b, acc0, 0, 0, 0);
        acc1 = __builtin_amdgcn_mfma_f32_32x32x16_f16(xl1, b, acc1, 0, 0, 0);
    }
    const float bv = bias[ct * 32 + r31];
    __syncthreads();
    #pragma unroll
    for (int r = 0; r < 16; r++) {
        int row = (r & 3) + 8 * (r >> 2) + 4 * g;
        float v0 = acc0[r] + bv;
        float v1 = acc1[r] + bv;
        if (OUTMODE == 0) { v0 = fmaxf(v0, 0.f); v1 = fmaxf(v1, 0.f); }
        _Float16 h0 = (_Float16)v0, h1 = (_Float16)v1;
        Hh[row][ct * 32 + r31] = h0;
        Hl[row][ct * 32 + r31] = (_Float16)(v0 - (float)h0);
        Hh[32 + row][ct * 32 + r31] = h1;
        Hl[32 + row][ct * 32 + r31] = (_Float16)(v1 - (float)h1);
    }
    __syncthreads();
}

// ---------------- mega kernel: trunk+pq1 [0,640) | kNN-mfma [640,1920), 512 thr ----------------
__global__ __launch_bounds__(512, 4) void k_main(const float* __restrict__ x,
    const _Float16* __restrict__ wfrag,
    const float* __restrict__ b0, const float* __restrict__ bmid,
    const float* __restrict__ bskip, const float* __restrict__ bfin,
    const float* __restrict__ wsig, const float* __restrict__ bsig,
    const _Float16* __restrict__ wfpq1, float* __restrict__ PQ,
    float* __restrict__ out,
    const unsigned short* __restrict__ xbh, const unsigned short* __restrict__ xbl,
    const float* __restrict__ cn, unsigned long long* __restrict__ pkey)
{
    __shared__ union SM {
        struct { _Float16 Hh[64][264]; _Float16 Hl[64][264];
                 _Float16 Dh[64][40];  _Float16 Dl[64][40]; } t;
        char knn[2][16384];
    } sm;
    const int tid = threadIdx.x;
    const int lane = tid & 63;
    const int wave = tid >> 6;
    const int r31 = lane & 31, g = lane >> 5;

    if (blockIdx.x < 640) {
        const int rowbase = blockIdx.x * 64;
        _Float16 (*Hh)[264] = sm.t.Hh;
        _Float16 (*Hl)[264] = sm.t.Hl;
        for (int s = tid; s < 64 * 32; s += 512) {
            int r = s >> 5, d = s & 31;
            float v = (d < 27) ? x[(size_t)(rowbase + r) * 90 + 63 + d] : 0.f;
            _Float16 h = (_Float16)v;
            sm.t.Dh[r][d] = h;
            sm.t.Dl[r][d] = (_Float16)(v - (float)h);
        }
        const _Float16* W = wfrag;
        mlayer64<0, 4, 0>(Hh, Hl, rowbase, x, W + (size_t)0   * 4096, b0,          lane, wave);
        mlayer64<16,0, 0>(Hh, Hl, rowbase, x, W + (size_t)4   * 4096, bmid + 0,    lane, wave);
        mlayer64<16,0, 0>(Hh, Hl, rowbase, x, W + (size_t)20  * 4096, bmid + 256,  lane, wave);
        mlayer64<16,0, 0>(Hh, Hl, rowbase, x, W + (size_t)36  * 4096, bmid + 512,  lane, wave);
        mlayer64<16,4, 0>(Hh, Hl, rowbase, x, W + (size_t)52  * 4096, bskip,       lane, wave);
        mlayer64<16,0, 0>(Hh, Hl, rowbase, x, W + (size_t)72  * 4096, bmid + 768,  lane, wave);
        mlayer64<16,0, 0>(Hh, Hl, rowbase, x, W + (size_t)88  * 4096, bmid + 1024, lane, wave);
        mlayer64<16,0, 0>(Hh, Hl, rowbase, x, W + (size_t)104 * 4096, bmid + 1280, lane, wave);
        if (wave < 2) {
            const int row = wave * 32 + r31;
            float s = 0.f;
            #pragma unroll
            for (int kk = 0; kk < 32; kk++) {
                half4 hh = *(const half4*)&Hh[row][g * 128 + kk * 4];
                half4 hl = *(const half4*)&Hl[row][g * 128 + kk * 4];
                float4 wv = *(const float4*)&wsig[g * 128 + kk * 4];
                s = fmaf((float)hh[0] + (float)hl[0], wv.x, s);
                s = fmaf((float)hh[1] + (float)hl[1], wv.y, s);
                s = fmaf((float)hh[2] + (float)hl[2], wv.z, s);
                s = fmaf((float)hh[3] + (float)hl[3], wv.w, s);
            }
            s += __shfl_xor(s, 32);
            if (lane < 32) out[(size_t)(rowbase + row) * 4 + 3] = s + bsig[0];
        }
        mlayer64<16,0, 2>(Hh, Hl, rowbase, x, W + (size_t)120 * 4096, bfin, lane, wave);
        {
            const int ct = wave;
            f32x16 p0, p1;
            #pragma unroll
            for (int r = 0; r < 16; r++) { p0[r] = 0.f; p1[r] = 0.f; }
            const _Float16* wp = wfpq1 + (size_t)ct * 18 * 512 + lane * 8;
            #pragma unroll
            for (int kc = 0; kc < 16; kc++) {
                half8 ah0 = *(const half8*)&Hh[r31][kc * 16 + g * 8];
                half8 al0 = *(const half8*)&Hl[r31][kc * 16 + g * 8];
                half8 ah1 = *(const half8*)&Hh[32 + r31][kc * 16 + g * 8];
                half8 al1 = *(const half8*)&Hl[32 + r31][kc * 16 + g * 8];
                half8 b = *(const half8*)(wp + kc * 512);
                p0 = __builtin_amdgcn_mfma_f32_32x32x16_f16(ah0, b, p0, 0, 0, 0);
                p1 = __builtin_amdgcn_mfma_f32_32x32x16_f16(ah1, b, p1, 0, 0, 0);
                p0 = __builtin_amdgcn_mfma_f32_32x32x16_f16(al0, b, p0, 0, 0, 0);
                p1 = __builtin_amdgcn_mfma_f32_32x32x16_f16(al1, b, p1, 0, 0, 0);
            }
            #pragma unroll
            for (int kc = 16; kc < 18; kc++) {
                const int dc = (kc - 16) * 16 + g * 8;
                half8 ah0 = *(const half8*)&sm.t.Dh[r31][dc];
                half8 al0 = *(const half8*)&sm.t.Dl[r31][dc];
                half8 ah1 = *(const half8*)&sm.t.Dh[32 + r31][dc];
                half8 al1 = *(const half8*)&sm.t.Dl[32 + r31][dc];
                half8 b = *(const half8*)(wp + kc * 512);
                p0 = __builtin_amdgcn_mfma_f32_32x32x16_f16(ah0, b, p0, 0, 0, 0);
                p1 = __builtin_amdgcn_mfma_f32_32x32x16_f16(ah1, b, p1, 0, 0, 0);
                p0 = __builtin_amdgcn_mfma_f32_32x32x16_f16(al0, b, p0, 0, 0, 0);
                p1 = __builtin_amdgcn_mfma_f32_32x32x16_f16(al1, b, p1, 0, 0, 0);
            }
            #pragma unroll
            for (int r = 0; r < 16; r++) {
                int row = (r & 3) + 8 * (r >> 2) + 4 * g;
                PQ[(size_t)(rowbase + row) * 256 + ct * 32 + r31] = p0[r];
                PQ[(size_t)(rowbase + 32 + row) * 256 + ct * 32 + r31] = p1[r];
            }
        }
    } else {
        const int bb = blockIdx.x - 640;
        const int gg = bb >> 6;
        const int rem = bb & 63;
        const int part = rem >> 4;
        const int qx = rem & 15;
        const int qt0 = qx * 128 + wave * 16;
        const size_t gbase = (size_t)gg * GSZ;
        const int lp = lane & 15;
        const int kgrp = lane >> 4;
        const int kg = kgrp << 3;
        char (*cbuf)[16384] = sm.knn;

        const size_t qb = (gbase + qt0 + lp) * 64;
        short8 ah0 = *(const short8*)(xbh + qb + kg);
        short8 ah1 = *(const short8*)(xbh + qb + 32 + kg);
        short8 al0 = *(const short8*)(xbl + qb + kg);
        short8 al1 = *(const short8*)(xbl + qb + 32 + kg);

        const int qp0 = qt0 + (kgrp << 2);

        unsigned int K00 = ~0u, I00 = 0, K01 = ~0u, I01 = 0, K02 = ~0u, I02 = 0;
        unsigned int K10 = ~0u, I10 = 0, K11 = ~0u, I11 = 0, K12 = ~0u, I12 = 0;
        unsigned int K20 = ~0u, I20 = 0, K21 = ~0u, I21 = 0, K22 = ~0u, I22 = 0;
        unsigned int K30 = ~0u, I30 = 0, K31 = ~0u, I31 = 0, K32 = ~0u, I32 = 0;

        const int cbeg = part * (GSZ / CPART);

        short8 st0, st1;
        {
            size_t cb = (gbase + cbeg + lane) * 64;
            st0 = *(const short8*)(xbh + cb + wave * 8);
            st1 = *(const short8*)(xbl + cb + wave * 8);
        }
        *(short8*)&cbuf[0][(wave << 10) + (lane << 4)] = st0;
        *(short8*)&cbuf[0][((8 + wave) << 10) + (lane << 4)] = st1;

        for (int ch = 0; ch < 8; ch++) {
            const int cur = ch & 1;
            __syncthreads();
            if (ch < 7) {
                size_t cb = (gbase + cbeg + (ch + 1) * 64 + lane) * 64;
                st0 = *(const short8*)(xbh + cb + wave * 8);
                st1 = *(const short8*)(xbl + cb + wave * 8);
            }
            const int cc0 = cbeg + ch * 64;
            #pragma unroll
            for (int ct = 0; ct < 4; ct++) {
                const int coff = ((ct * 16 + lp) << 4);
                short8 bh0 = *(const short8*)&cbuf[cur][((kgrp)      << 10) + coff];
                short8 bh1 = *(const short8*)&cbuf[cur][((4 + kgrp)  << 10) + coff];
                short8 bl0 = *(const short8*)&cbuf[cur][((8 + kgrp)  << 10) + coff];
                short8 bl1 = *(const short8*)&cbuf[cur][((12 + kgrp) << 10) + coff];
                f32x4 acc = {0.f, 0.f, 0.f, 0.f};
                acc = __builtin_amdgcn_mfma_f32_16x16x32_bf16(ah0, bh0, acc, 0, 0, 0);
                acc = __builtin_amdgcn_mfma_f32_16x16x32_bf16(ah1, bh1, acc, 0, 0, 0);
                acc = __builtin_amdgcn_mfma_f32_16x16x32_bf16(al0, bh0, acc, 0, 0, 0);
                acc = __builtin_amdgcn_mfma_f32_16x16x32_bf16(al1, bh1, acc, 0, 0, 0);
                acc = __builtin_amdgcn_mfma_f32_16x16x32_bf16(ah0, bl0, acc, 0, 0, 0);
                acc = __builtin_amdgcn_mfma_f32_16x16x32_bf16(ah1, bl1, acc, 0, 0, 0);
                const float cnv = cn[gbase + cc0 + ct * 16 + lp];
                const int cpos = cc0 + ct * 16 + lp;
                const unsigned int ci = (unsigned int)cpos;
                {
                    unsigned int k = fkey(fmaf(-2.f, acc[0], cnv));
                    k = (cpos == qp0 + 0) ? 0xFFFFFFFFu : k;
                    ins3p(k, ci, K00, I00, K01, I01, K02, I02);
                }
                {
                    unsigned int k = fkey(fmaf(-2.f, acc[1], cnv));
                    k = (cpos == qp0 + 1) ? 0xFFFFFFFFu : k;
                    ins3p(k, ci, K10, I10, K11, I11, K12, I12);
                }
                {
                    unsigned int k = fkey(fmaf(-2.f, acc[2], cnv));
                    k = (cpos == qp0 + 2) ? 0xFFFFFFFFu : k;
                    ins3p(k, ci, K20, I20, K21, I21, K22, I22);
                }
                {
                    unsigned int k = fkey(fmaf(-2.f, acc[3], cnv));
                    k = (cpos == qp0 + 3) ? 0xFFFFFFFFu : k;
                    ins3p(k, ci, K30, I30, K31, I31, K32, I32);
                }
            }
            if (ch < 7) {
                *(short8*)&cbuf[cur ^ 1][(wave << 10) + (lane << 4)] = st0;
                *(short8*)&cbuf[cur ^ 1][((8 + wave) << 10) + (lane << 4)] = st1;
            }
        }

        mergerow(K00, I00, K01, I01, K02, I02);
        mergerow(K10, I10, K11, I11, K12, I12);
        mergerow(K20, I20, K21, I21, K22, I22);
        mergerow(K30, I30, K31, I31, K32, I32);

        if (lp == 0) {
            size_t ob = (gbase + (size_t)qp0) * (CPART * 3) + part * 3;
            pkey[ob + 0]  = ((unsigned long long)K00 << 32) | I00;
            pkey[ob + 1]  = ((unsigned long long)K01 << 32) | I01;
            pkey[ob + 2]  = ((unsigned long long)K02 << 32) | I02;
            pkey[ob + 12] = ((unsigned long long)K10 << 32) | I10;
            pkey[ob + 13] = ((unsigned long long)K11 << 32) | I11;
            pkey[ob + 14] = ((unsigned long long)K12 << 32) | I12;
            pkey[ob + 24] = ((unsigned long long)K20 << 32) | I20;
            pkey[ob + 25] = ((unsigned long long)K21 << 32) | I21;
            pkey[ob + 26] = ((unsigned long long)K22 << 32) | I22;
            pkey[ob + 36] = ((unsigned long long)K30 << 32) | I30;
            pkey[ob + 37] = ((unsigned long long)K31 << 32) | I31;
            pkey[ob + 38] = ((unsigned long long)K32 << 32) | I32;
        }
    }
}

// ---------------- kNN merge ----------------
__device__ __forceinline__ void ins3u(unsigned long long k,
    unsigned long long& k0, unsigned long long& k1, unsigned long long& k2)
{
    if (k < k0)      { k2 = k1; k1 = k0; k0 = k; }
    else if (k < k1) { k2 = k1; k1 = k; }
    else if (k < k2) { k2 = k; }
}

__global__ void k_knn_merge(const unsigned long long* __restrict__ pkey,
                            const int* __restrict__ grp, int* __restrict__ nbr)
{
    int t = blockIdx.x * 256 + threadIdx.x;
    if (t >= NGRP * GSZ) return;
    int g = t >> 11;
    unsigned long long k0 = ~0ull, k1 = ~0ull, k2 = ~0ull;
    const unsigned long long* pk = pkey + (size_t)t * (CPART * 3);
    #pragma unroll
    for (int r = 0; r < CPART * 3; r++) ins3u(pk[r], k0, k1, k2);
    int qi = grp[t];
    nbr[(size_t)qi * 3 + 0] = grp[(g << 11) + (int)(k0 & 0xFFFFFFFFull)];
    nbr[(size_t)qi * 3 + 1] = grp[(g << 11) + (int)(k1 & 0xFFFFFFFFull)];
    nbr[(size_t)qi * 3 + 2] = grp[(g << 11) + (int)(k2 & 0xFFFFFFFFull)];
}

// ---------------- edge conv via MFMA (+ fused pq2 when RGB==0) ----------------
template<int RGB>
__global__ __launch_bounds__(256) void k_edge_mfma(const float* __restrict__ PQ,
    const float* __restrict__ b1, const _Float16* __restrict__ wf2,
    const float* __restrict__ b2, const int* __restrict__ nbr,
    const _Float16* __restrict__ wfpq2, float* __restrict__ pqout,
    const float* __restrict__ wrgb, const float* __restrict__ brgb,
    float* __restrict__ out)
{
    __shared__ _Float16 Hh[128][136];
    __shared__ _Float16 Hl[128][136];
    const int tid = threadIdx.x;
    const int lane = tid & 63, wave = tid >> 6;
    const int r31 = lane & 31, g = lane >> 5;
    const int n0 = blockIdx.x * 32;

    for (int s = tid; s < 128 * 32; s += 256) {
        int e = s >> 5, c4 = (s & 31) << 2;
        int n = e >> 2, jj = e & 3;
        half4 zh = {(_Float16)0.f, (_Float16)0.f, (_Float16)0.f, (_Float16)0.f};
        if (jj < 3) {
            int i = n0 + n;
            int j = nbr[(size_t)i * 3 + jj];
            float4 p  = *(const float4*)&PQ[(size_t)i * 256 + c4];
            float4 qi = *(const float4*)&PQ[(size_t)i * 256 + 128 + c4];
            float4 qj = *(const float4*)&PQ[(size_t)j * 256 + 128 + c4];
            float4 bv = *(const float4*)&b1[c4];
            float v[4];
            v[0] = fmaxf(p.x + bv.x + qj.x - qi.x, 0.f);
            v[1] = fmaxf(p.y + bv.y + qj.y - qi.y, 0.f);
            v[2] = fmaxf(p.z + bv.z + qj.z - qi.z, 0.f);
            v[3] = fmaxf(p.w + bv.w + qj.w - qi.w, 0.f);
            half4 hh, hl;
            #pragma unroll
            for (int u = 0; u < 4; u++) {
                _Float16 h = (_Float16)v[u];
                hh[u] = h;
                hl[u] = (_Float16)(v[u] - (float)h);
            }
            *(half4*)&Hh[e][c4] = hh;
            *(half4*)&Hl[e][c4] = hl;
        } else {
            *(half4*)&Hh[e][c4] = zh;
            *(half4*)&Hl[e][c4] = zh;
        }
    }
    __syncthreads();

    const int ct = wave;
    f32x16 a0, a1, a2, a3;
    #pragma unroll
    for (int r = 0; r < 16; r++) { a0[r] = 0.f; a1[r] = 0.f; a2[r] = 0.f; a3[r] = 0.f; }
    const _Float16* wp = wf2 + (size_t)ct * 8 * 512 + lane * 8;
    #pragma unroll
    for (int kc = 0; kc < 8; kc++) {
        half8 b = *(const half8*)(wp + kc * 512);
        half8 h0 = *(const half8*)&Hh[r31][kc * 16 + g * 8];
        half8 l0 = *(const half8*)&Hl[r31][kc * 16 + g * 8];
        a0 = __builtin_amdgcn_mfma_f32_32x32x16_f16(h0, b, a0, 0, 0, 0);
        a0 = __builtin_amdgcn_mfma_f32_32x32x16_f16(l0, b, a0, 0, 0, 0);
        half8 h1 = *(const half8*)&Hh[32 + r31][kc * 16 + g * 8];
        half8 l1 = *(const half8*)&Hl[32 + r31][kc * 16 + g * 8];
        a1 = __builtin_amdgcn_mfma_f32_32x32x16_f16(h1, b, a1, 0, 0, 0);
        a1 = __builtin_amdgcn_mfma_f32_32x32x16_f16(l1, b, a1, 0, 0, 0);
        half8 h2 = *(const half8*)&Hh[64 + r31][kc * 16 + g * 8];
        half8 l2 = *(const half8*)&Hl[64 + r31][kc * 16 + g * 8];
        a2 = __builtin_amdgcn_mfma_f32_32x32x16_f16(h2, b, a2, 0, 0, 0);
        a2 = __builtin_amdgcn_mfma_f32_32x32x16_f16(l2, b, a2, 0, 0, 0);
        half8 h3 = *(const half8*)&Hh[96 + r31][kc * 16 + g * 8];
        half8 l3 = *(const half8*)&Hl[96 + r31][kc * 16 + g * 8];
        a3 = __builtin_amdgcn_mfma_f32_32x32x16_f16(h3, b, a3, 0, 0, 0);
        a3 = __builtin_amdgcn_mfma_f32_32x32x16_f16(l3, b, a3, 0, 0, 0);
    }
    const float bv = b2[ct * 32 + r31];
    const int col = ct * 32 + r31;

    if (!RGB) {
        __syncthreads();
        #pragma unroll
        for (int q = 0; q < 4; q++) {
            float s0 = fmaxf(a0[4*q] + bv, 0.f) + fmaxf(a0[4*q+1] + bv, 0.f) + fmaxf(a0[4*q+2] + bv, 0.f);
            float s1 = fmaxf(a1[4*q] + bv, 0.f) + fmaxf(a1[4*q+1] + bv, 0.f) + fmaxf(a1[4*q+2] + bv, 0.f);
            float s2 = fmaxf(a2[4*q] + bv, 0.f) + fmaxf(a2[4*q+1] + bv, 0.f) + fmaxf(a2[4*q+2] + bv, 0.f);
            float s3 = fmaxf(a3[4*q] + bv, 0.f) + fmaxf(a3[4*q+1] + bv, 0.f) + fmaxf(a3[4*q+2] + bv, 0.f);
            int nq = 2 * q + g;
            float v0 = s0 * (1.f / 3.f), v1 = s1 * (1.f / 3.f);
            float v2 = s2 * (1.f / 3.f), v3 = s3 * (1.f / 3.f);
            _Float16 h0 = (_Float16)v0, h1 = (_Float16)v1, h2 = (_Float16)v2, h3 = (_Float16)v3;
            Hh[0  + nq][col] = h0; Hl[0  + nq][col] = (_Float16)(v0 - (float)h0);
            Hh[8  + nq][col] = h1; Hl[8  + nq][col] = (_Float16)(v1 - (float)h1);
            Hh[16 + nq][col] = h2; Hl[16 + nq][col] = (_Float16)(v2 - (float)h2);
            Hh[24 + nq][col] = h3; Hl[24 + nq][col] = (_Float16)(v3 - (float)h3);
        }
        __syncthreads();
        const int ct0 = wave * 2;
        f32x16 p0, p1;
        #pragma unroll
        for (int r = 0; r < 16; r++) { p0[r] = 0.f; p1[r] = 0.f; }
        const _Float16* wq0 = wfpq2 + (size_t)ct0 * 8 * 512 + lane * 8;
        const _Float16* wq1 = wq0 + (size_t)8 * 512;
        #pragma unroll
        for (int kc = 0; kc < 8; kc++) {
            half8 ah = *(const half8*)&Hh[r31][kc * 16 + g * 8];
            half8 al = *(const half8*)&Hl[r31][kc * 16 + g * 8];
            half8 b0v = *(const half8*)(wq0 + kc * 512);
            half8 b1v = *(const half8*)(wq1 + kc * 512);
            p0 = __builtin_amdgcn_mfma_f32_32x32x16_f16(ah, b0v, p0, 0, 0, 0);
            p1 = __builtin_amdgcn_mfma_f32_32x32x16_f16(ah, b1v, p1, 0, 0, 0);
            p0 = __builtin_amdgcn_mfma_f32_32x32x16_f16(al, b0v, p0, 0, 0, 0);
            p1 = __builtin_amdgcn_mfma_f32_32x32x16_f16(al, b1v, p1, 0, 0, 0);
        }
        #pragma unroll
        for (int r = 0; r < 16; r++) {
            int row = (r & 3) + 8 * (r >> 2) + 4 * g;
            pqout[(size_t)(n0 + row) * 256 + ct0 * 32 + r31] = p0[r];
            pqout[(size_t)(n0 + row) * 256 + ct0 * 32 + 32 + r31] = p1[r];
        }
    } else {
        __syncthreads();
        float* d2L = (float*)&Hh[0][0];
        #pragma unroll
        for (int q = 0; q < 4; q++) {
            float s0 = fmaxf(a0[4*q] + bv, 0.f) + fmaxf(a0[4*q+1] + bv, 0.f) + fmaxf(a0[4*q+2] + bv, 0.f);
            float s1 = fmaxf(a1[4*q] + bv, 0.f) + fmaxf(a1[4*q+1] + bv, 0.f) + fmaxf(a1[4*q+2] + bv, 0.f);
            float s2 = fmaxf(a2[4*q] + bv, 0.f) + fmaxf(a2[4*q+1] + bv, 0.f) + fmaxf(a2[4*q+2] + bv, 0.f);
            float s3 = fmaxf(a3[4*q] + bv, 0.f) + fmaxf(a3[4*q+1] + bv, 0.f) + fmaxf(a3[4*q+2] + bv, 0.f);
            int nq = 2 * q + g;
            d2L[(0  + nq) * 132 + col] = s0 * (1.f / 3.f);
            d2L[(8  + nq) * 132 + col] = s1 * (1.f / 3.f);
            d2L[(16 + nq) * 132 + col] = s2 * (1.f / 3.f);
            d2L[(24 + nq) * 132 + col] = s3 * (1.f / 3.f);
        }
        __syncthreads();
        if (tid < 96) {
            int n = tid / 3, ch = tid - 3 * (tid / 3);
            float s = brgb[ch];
            for (int k = 0; k < 128; k++) s = fmaf(d2L[n * 132 + k], wrgb[k * 3 + ch], s);
            out[(size_t)(n0 + n) * 4 + ch] = 1.f / (1.f + expf(-s));
        }
    }
}

// ---------------- launch ----------------
extern "C" void kernel_launch(void* const* d_in, const int* in_sizes, int n_in,
                              void* d_out, int out_size, void* d_ws, size_t ws_size,
                              hipStream_t stream)
{
    const float* x     = (const float*)d_in[0];
    const int*   bid   = (const int*)d_in[1];
    const float* w0    = (const float*)d_in[2];
    const float* b0    = (const float*)d_in[3];
    const float* wmid  = (const float*)d_in[4];
    const float* bmid  = (const float*)d_in[5];
    const float* wskip = (const float*)d_in[6];
    const float* bskip = (const float*)d_in[7];
    const float* wfin  = (const float*)d_in[8];
    const float* bfin  = (const float*)d_in[9];
    const float* wsig  = (const float*)d_in[10];
    const float* bsig  = (const float*)d_in[11];
    const float* e1w1  = (const float*)d_in[12];
    const float* e1b1  = (const float*)d_in[13];
    const float* e1w2  = (const float*)d_in[14];
    const float* e1b2  = (const float*)d_in[15];
    const float* e2w1  = (const float*)d_in[16];
    const float* e2b1  = (const float*)d_in[17];
    const float* e2w2  = (const float*)d_in[18];
    const float* e2b2  = (const float*)d_in[19];
    const float* wrgb  = (const float*)d_in[20];
    const float* brgb  = (const float*)d_in[21];
    float* out = (float*)d_out;

    char* ws = (char*)d_ws;
    int* grp = (int*)(ws + 256);
    int* nbr = (int*)(ws + 164096);
    _Float16* wfpq1 = (_Float16*)(ws + 655616);
    _Float16* wfpq2 = (_Float16*)(ws + 950528);
    _Float16* wfe1  = (_Float16*)(ws + 1081600);
    _Float16* wfe2  = (_Float16*)(ws + 1147136);
    float* bufA = (float*)(ws + (2 << 20));
    float* bufB = bufA + (size_t)B_TOTAL * 256;

    unsigned short* xbh = (unsigned short*)bufA;
    unsigned short* xbl = xbh + (size_t)B_TOTAL * 64;
    float* cn   = (float*)(xbl + (size_t)B_TOTAL * 64);
    unsigned long long* pkey = (unsigned long long*)(cn + B_TOTAL);
    _Float16* wfrag = (_Float16*)((char*)bufA + ((size_t)20 << 20));
    float* PQ  = bufB;
    float* PQ2 = bufA;

    k_prep<<<2720, 256, 0, stream>>>(w0, wmid, wskip, wfin, wfrag,
                                     e1w1, wfpq1, e2w1, wfpq2, e1w2, wfe1, e2w2, wfe2);
    k_scatter_det<<<NGRP, 1024, 0, stream>>>(bid, grp);
    k_gather<<<dim3(GSZ / 128, NGRP), 256, 0, stream>>>(x, grp, xbh, xbl, cn);
    k_main<<<640 + 1280, 512, 0, stream>>>(x, wfrag, b0, bmid, bskip, bfin,
                                           wsig, bsig, wfpq1, PQ, out,
                                           xbh, xbl, cn, pkey);
    k_knn_merge<<<(NGRP * GSZ + 255) / 256, 256, 0, stream>>>(pkey, grp, nbr);
    k_edge_mfma<0><<<B_TOTAL / 32, 256, 0, stream>>>(PQ, e1b1, wfe1, e1b2, nbr,
                                                     wfpq2, PQ2, nullptr, nullptr, nullptr);
    k_edge_mfma<1><<<B_TOTAL / 32, 256, 0, stream>>>(PQ2, e2b1, wfe2, e2b2, nbr,
                                                     nullptr, nullptr, wrgb, brgb, out);
}